// Round 1
// 1507.510 us; speedup vs baseline: 1.5638x; 1.5638x over previous
//
#include <hip/hip_runtime.h>
#include <hip/hip_bf16.h>

// Model dims (fixed by the reference)
#define BATCH  4
#define SEQ    512
#define TOK    (BATCH*SEQ)     // 2048
#define HID    512
#define NHEAD  8
#define HEAD   64
#define FFDIM  2048
#define NLAYER 12
#define SPAN2  1024            // 2*SPAN
#define VOCAB  25
#define LNEPS  1e-7f
#define NEG_BIG -3.0e38f

typedef __attribute__((ext_vector_type(8))) short bf16x8;   // 8 bf16 = 4 VGPRs
typedef __attribute__((ext_vector_type(4))) float floatx4;

#define MFMA16(a, b, c) __builtin_amdgcn_mfma_f32_16x16x32_bf16((a), (b), (c), 0, 0, 0)

__device__ __forceinline__ float b2f(unsigned short u) {
    return __uint_as_float(((unsigned int)u) << 16);
}
__device__ __forceinline__ unsigned short f2b(float f) {
    __hip_bfloat16 h = __float2bfloat16(f);
    return *(unsigned short*)&h;
}

// ---------------- block reductions (blockDim = 256, 1-D) ----------------
__device__ __forceinline__ float block_reduce_sum(float v, float* red) {
    int tid = threadIdx.x;
    red[tid] = v; __syncthreads();
    for (int s = 128; s > 0; s >>= 1) { if (tid < s) red[tid] += red[tid + s]; __syncthreads(); }
    float r = red[0]; __syncthreads();
    return r;
}

// ---------------- embedding gather + LN + mask (writes fp32 h and bf16 hb) ----------------
__global__ void embed_ln_kernel(const int* __restrict__ x, const int* __restrict__ am,
                                const float* __restrict__ word_emb,
                                const float* __restrict__ g, const float* __restrict__ bb,
                                float* __restrict__ h, unsigned short* __restrict__ hb) {
    __shared__ float red[256];
    int t = blockIdx.x, tid = threadIdx.x;
    const float* we = word_emb + (size_t)x[t] * HID;
    float v1 = we[tid], v2 = we[tid + 256];
    float mean = block_reduce_sum(v1 + v2, red) * (1.0f / HID);
    float d1 = v1 - mean, d2 = v2 - mean;
    float var = block_reduce_sum(d1 * d1 + d2 * d2, red) * (1.0f / HID);
    float rstd = rsqrtf(var + LNEPS);
    float maskf = (float)am[t];
    size_t base = (size_t)t * HID;
    float o1 = (d1 * rstd * g[tid]       + bb[tid])       * maskf;
    float o2 = (d2 * rstd * g[tid + 256] + bb[tid + 256]) * maskf;
    h[base + tid] = o1;        h[base + tid + 256] = o2;
    hb[base + tid] = f2b(o1);  hb[base + tid + 256] = f2b(o2);
}

// ---------------- residual add + LN, single tmp (fallback path) ----------------
__global__ void add_ln_kernel(const float* __restrict__ tmp,
                              const float* __restrict__ g, const float* __restrict__ bb,
                              float* __restrict__ h, unsigned short* __restrict__ hb) {
    __shared__ float red[256];
    int t = blockIdx.x, tid = threadIdx.x;
    size_t base = (size_t)t * HID;
    float v1 = tmp[base + tid] + h[base + tid];
    float v2 = tmp[base + tid + 256] + h[base + tid + 256];
    float mean = block_reduce_sum(v1 + v2, red) * (1.0f / HID);
    float d1 = v1 - mean, d2 = v2 - mean;
    float var = block_reduce_sum(d1 * d1 + d2 * d2, red) * (1.0f / HID);
    float rstd = rsqrtf(var + LNEPS);
    float o1 = d1 * rstd * g[tid]       + bb[tid];
    float o2 = d2 * rstd * g[tid + 256] + bb[tid + 256];
    h[base + tid] = o1;        h[base + tid + 256] = o2;
    hb[base + tid] = f2b(o1);  hb[base + tid + 256] = f2b(o2);
}

// ---------------- residual add + LN, two split-K partials ----------------
__global__ void add_ln2_kernel(const float* __restrict__ t1a, const float* __restrict__ t1b,
                               const float* __restrict__ g, const float* __restrict__ bb,
                               float* __restrict__ h, unsigned short* __restrict__ hb) {
    __shared__ float red[256];
    int t = blockIdx.x, tid = threadIdx.x;
    size_t base = (size_t)t * HID;
    float v1 = t1a[base + tid] + t1b[base + tid] + h[base + tid];
    float v2 = t1a[base + tid + 256] + t1b[base + tid + 256] + h[base + tid + 256];
    float mean = block_reduce_sum(v1 + v2, red) * (1.0f / HID);
    float d1 = v1 - mean, d2 = v2 - mean;
    float var = block_reduce_sum(d1 * d1 + d2 * d2, red) * (1.0f / HID);
    float rstd = rsqrtf(var + LNEPS);
    float o1 = d1 * rstd * g[tid]       + bb[tid];
    float o2 = d2 * rstd * g[tid + 256] + bb[tid + 256];
    h[base + tid] = o1;        h[base + tid + 256] = o2;
    hb[base + tid] = f2b(o1);  hb[base + tid + 256] = f2b(o2);
}

// ---------------- fp32 -> bf16 convert (rel_emb, n multiple of 1024) ----------------
__global__ void cvt_rel_kernel(const float* __restrict__ in, unsigned short* __restrict__ out) {
    int i = (blockIdx.x * 256 + threadIdx.x) * 4;
    float4 v = *(const float4*)(in + i);
    out[i] = f2b(v.x); out[i+1] = f2b(v.y); out[i+2] = f2b(v.z); out[i+3] = f2b(v.w);
}

// ---------------- transpose+convert: W[K][N] fp32 -> Wt[N][K] bf16, blockIdx.z = layer ----------------
__global__ void tcvt_kernel(const float* __restrict__ in, unsigned short* __restrict__ out,
                            int K, int N) {
    __shared__ float tile[32][33];
    int l = blockIdx.z;
    const float* ip = in + (size_t)l * K * N;
    unsigned short* op = out + (size_t)l * K * N;
    int kb = blockIdx.y * 32, nb = blockIdx.x * 32;
    int tx = threadIdx.x, ty = threadIdx.y;   // block (32,8)
    #pragma unroll
    for (int i = 0; i < 32; i += 8) tile[ty + i][tx] = ip[(size_t)(kb + ty + i) * N + nb + tx];
    __syncthreads();
    #pragma unroll
    for (int i = 0; i < 32; i += 8) op[(size_t)(nb + ty + i) * K + kb + tx] = f2b(tile[tx][ty + i]);
}

// six [12][512][512] weight arrays in one launch; z = l*6 + w; out contiguous [w][l][512][512]
__global__ void tcvt6_kernel(const float* __restrict__ Wq, const float* __restrict__ Wk,
                             const float* __restrict__ Wv, const float* __restrict__ Wpk,
                             const float* __restrict__ Wpq, const float* __restrict__ Wo,
                             unsigned short* __restrict__ out) {
    __shared__ float tile[32][33];
    int z = blockIdx.z, l = z / 6, w = z - l * 6;
    const float* src = w == 0 ? Wq : w == 1 ? Wk : w == 2 ? Wv : w == 3 ? Wpk : w == 4 ? Wpq : Wo;
    const float* ip = src + (size_t)l * HID * HID;
    unsigned short* op = out + ((size_t)w * NLAYER + l) * HID * HID;
    int kb = blockIdx.y * 32, nb = blockIdx.x * 32;
    int tx = threadIdx.x, ty = threadIdx.y;
    #pragma unroll
    for (int i = 0; i < 32; i += 8) tile[ty + i][tx] = ip[(size_t)(kb + ty + i) * HID + nb + tx];
    __syncthreads();
    #pragma unroll
    for (int i = 0; i < 32; i += 8) op[(size_t)(nb + ty + i) * HID + kb + tx] = f2b(tile[tx][ty + i]);
}

// ---------------- shared 64x64 tile core: A[M][K] bf16 x Bt[N][K] bf16 ----------------
__device__ __forceinline__ void gemm_tile_bt(
    const unsigned short* __restrict__ A, const unsigned short* __restrict__ Bt,
    int row0, int col0, int K, int kbeg, int kend,
    floatx4 (&acc)[2][2], unsigned short (&As)[64][72], unsigned short (&Bs)[64][72]) {
    int tid = threadIdx.x;
    int lane = tid & 63, wid = tid >> 6;
    int wm = wid >> 1, wn = wid & 1;
    int m16 = lane & 15, quad = lane >> 4;
    int sr = tid >> 2, sc = (tid & 3) << 4;          // staging: row, 16 bf16 cols
    const unsigned short* Ag = A + (size_t)(row0 + sr) * K + sc;
    const unsigned short* Bg = Bt + (size_t)(col0 + sr) * K + sc;
    for (int k0 = kbeg; k0 < kend; k0 += 64) {
        uint4 av0 = *(const uint4*)(Ag + k0);
        uint4 av1 = *(const uint4*)(Ag + k0 + 8);
        uint4 bv0 = *(const uint4*)(Bg + k0);
        uint4 bv1 = *(const uint4*)(Bg + k0 + 8);
        *(uint4*)&As[sr][sc]     = av0;
        *(uint4*)&As[sr][sc + 8] = av1;
        *(uint4*)&Bs[sr][sc]     = bv0;
        *(uint4*)&Bs[sr][sc + 8] = bv1;
        __syncthreads();
        #pragma unroll
        for (int kk = 0; kk < 2; kk++) {
            bf16x8 a0 = *(const bf16x8*)&As[wm * 32 + m16][kk * 32 + quad * 8];
            bf16x8 a1 = *(const bf16x8*)&As[wm * 32 + 16 + m16][kk * 32 + quad * 8];
            bf16x8 b0 = *(const bf16x8*)&Bs[wn * 32 + m16][kk * 32 + quad * 8];
            bf16x8 b1 = *(const bf16x8*)&Bs[wn * 32 + 16 + m16][kk * 32 + quad * 8];
            acc[0][0] = MFMA16(a0, b0, acc[0][0]);
            acc[0][1] = MFMA16(a0, b1, acc[0][1]);
            acc[1][0] = MFMA16(a1, b0, acc[1][0]);
            acc[1][1] = MFMA16(a1, b1, acc[1][1]);
        }
        __syncthreads();
    }
}

// ---------------- generic bf16-weight GEMM, optional split-K over blockIdx.z ----------------
template<bool OUT_BF16, bool GELU, int SPLITK>
__global__ __launch_bounds__(256) void gemm_bt(
    const unsigned short* __restrict__ A, const unsigned short* __restrict__ Bt,
    const float* __restrict__ bias, void* __restrict__ Cp, int N, int K) {
    __shared__ unsigned short As[64][72], Bs[64][72];
    int row0 = blockIdx.y * 64, col0 = blockIdx.x * 64;
    int kseg = K / SPLITK;
    int kbeg = kseg * blockIdx.z, kend = kbeg + kseg;
    floatx4 acc[2][2];
    #pragma unroll
    for (int mi = 0; mi < 2; mi++)
        #pragma unroll
        for (int ni = 0; ni < 2; ni++) acc[mi][ni] = (floatx4){0.f, 0.f, 0.f, 0.f};
    gemm_tile_bt(A, Bt, row0, col0, K, kbeg, kend, acc, As, Bs);

    int tid = threadIdx.x, lane = tid & 63, wid = tid >> 6;
    int wm = wid >> 1, wn = wid & 1, m16 = lane & 15, quad = lane >> 4;
    size_t outoff = (size_t)blockIdx.z * (size_t)(gridDim.y << 6) * N;
    #pragma unroll
    for (int ni = 0; ni < 2; ni++) {
        int colg = col0 + wn * 32 + ni * 16 + m16;
        float bval = (SPLITK == 1 || blockIdx.z == 0) ? bias[colg] : 0.0f;
        #pragma unroll
        for (int mi = 0; mi < 2; mi++) {
            #pragma unroll
            for (int r = 0; r < 4; r++) {
                int rowg = row0 + wm * 32 + mi * 16 + quad * 4 + r;
                float v = acc[mi][ni][r] + bval;
                if (GELU) v = 0.5f * v * (1.0f + erff(v * 0.70710678118654752f));
                if (OUT_BF16) ((unsigned short*)Cp)[(size_t)rowg * N + colg] = f2b(v);
                else          ((float*)Cp)[outoff + (size_t)rowg * N + colg] = v;
            }
        }
    }
}

// ---------------- fused Q,K,V,Pk,Pq projections: 1024 workgroups, one launch ----------------
__global__ __launch_bounds__(256) void qkvp_gemm(
    const unsigned short* __restrict__ hb, const unsigned short* __restrict__ relb,
    const unsigned short* __restrict__ Wqt, const unsigned short* __restrict__ Wkt,
    const unsigned short* __restrict__ Wvt, const unsigned short* __restrict__ Wpkt,
    const unsigned short* __restrict__ Wpqt,
    const float* __restrict__ bq, const float* __restrict__ bk, const float* __restrict__ bv,
    const float* __restrict__ bpk, const float* __restrict__ bpq,
    unsigned short* __restrict__ qb, unsigned short* __restrict__ kb,
    unsigned short* __restrict__ vb, unsigned short* __restrict__ pkb,
    unsigned short* __restrict__ pqb) {
    __shared__ unsigned short As[64][72], Bs[64][72];
    int gid = blockIdx.x;
    const unsigned short* A; const unsigned short* Bt; const float* bias; unsigned short* C;
    int trow, tcol;
    if (gid < 768) {                       // Q,K,V: M=2048 -> 32x8 tiles each
        int op = gid >> 8, t = gid & 255;
        trow = t >> 3; tcol = t & 7;
        A = hb;
        Bt   = op == 0 ? Wqt : op == 1 ? Wkt : Wvt;
        bias = op == 0 ? bq  : op == 1 ? bk  : bv;
        C    = op == 0 ? qb  : op == 1 ? kb  : vb;
    } else {                               // Pk,Pq: M=1024 -> 16x8 tiles each
        int g = gid - 768, op = g >> 7, t = g & 127;
        trow = t >> 3; tcol = t & 7;
        A = relb;
        Bt   = op ? Wpqt : Wpkt;
        bias = op ? bpq  : bpk;
        C    = op ? pqb  : pkb;
    }
    floatx4 acc[2][2];
    #pragma unroll
    for (int mi = 0; mi < 2; mi++)
        #pragma unroll
        for (int ni = 0; ni < 2; ni++) acc[mi][ni] = (floatx4){0.f, 0.f, 0.f, 0.f};
    gemm_tile_bt(A, Bt, trow * 64, tcol * 64, HID, 0, HID, acc, As, Bs);

    int tid = threadIdx.x, lane = tid & 63, wid = tid >> 6;
    int wm = wid >> 1, wn = wid & 1, m16 = lane & 15, quad = lane >> 4;
    #pragma unroll
    for (int ni = 0; ni < 2; ni++) {
        int colg = tcol * 64 + wn * 32 + ni * 16 + m16;
        float bval = bias[colg];
        #pragma unroll
        for (int mi = 0; mi < 2; mi++) {
            #pragma unroll
            for (int r = 0; r < 4; r++) {
                int rowg = trow * 64 + wm * 32 + mi * 16 + quad * 4 + r;
                C[(size_t)rowg * HID + colg] = f2b(acc[mi][ni][r] + bval);
            }
        }
    }
}

// ---------------- fallback MFMA GEMM: B fp32 inline-converted (baseline path) ----------------
template<bool OUT_BF16, bool GELU>
__global__ __launch_bounds__(256) void mfma_gemm(
    const unsigned short* __restrict__ A, const float* __restrict__ B,
    const float* __restrict__ bias, void* __restrict__ Cp, int N, int K) {
    __shared__ unsigned short As[64][72];   // [m][k]
    __shared__ unsigned short Bs[64][72];   // [n][k]
    int tid = threadIdx.x;
    int lane = tid & 63, wid = tid >> 6;
    int wm = wid >> 1, wn = wid & 1;
    int row0 = blockIdx.y * 64, col0 = blockIdx.x * 64;
    int m16 = lane & 15, quad = lane >> 4;

    int ar = tid >> 2, ac = (tid & 3) << 4;
    int bk = (tid >> 3) << 1, bn = (tid & 7) << 3;

    const unsigned short* Ag = A + (size_t)(row0 + ar) * K + ac;
    const float* Bg = B + (size_t)bk * N + col0 + bn;

    floatx4 acc[2][2];
    #pragma unroll
    for (int mi = 0; mi < 2; mi++)
        #pragma unroll
        for (int ni = 0; ni < 2; ni++) acc[mi][ni] = (floatx4){0.f, 0.f, 0.f, 0.f};

    for (int k0 = 0; k0 < K; k0 += 64) {
        uint4 av0 = *(const uint4*)(Ag + k0);
        uint4 av1 = *(const uint4*)(Ag + k0 + 8);
        const float* br0 = Bg + (size_t)k0 * N;
        const float* br1 = br0 + N;
        float4 b00 = *(const float4*)br0, b01 = *(const float4*)(br0 + 4);
        float4 b10 = *(const float4*)br1, b11 = *(const float4*)(br1 + 4);
        *(uint4*)&As[ar][ac] = av0;
        *(uint4*)&As[ar][ac + 8] = av1;
        float lo[8] = {b00.x, b00.y, b00.z, b00.w, b01.x, b01.y, b01.z, b01.w};
        float hi[8] = {b10.x, b10.y, b10.z, b10.w, b11.x, b11.y, b11.z, b11.w};
        #pragma unroll
        for (int i = 0; i < 8; i++) {
            unsigned int p = (unsigned int)f2b(lo[i]) | ((unsigned int)f2b(hi[i]) << 16);
            *(unsigned int*)&Bs[bn + i][bk] = p;
        }
        __syncthreads();
        #pragma unroll
        for (int kk = 0; kk < 2; kk++) {
            bf16x8 a0 = *(const bf16x8*)&As[wm * 32 + m16][kk * 32 + quad * 8];
            bf16x8 a1 = *(const bf16x8*)&As[wm * 32 + 16 + m16][kk * 32 + quad * 8];
            bf16x8 b0 = *(const bf16x8*)&Bs[wn * 32 + m16][kk * 32 + quad * 8];
            bf16x8 b1 = *(const bf16x8*)&Bs[wn * 32 + 16 + m16][kk * 32 + quad * 8];
            acc[0][0] = MFMA16(a0, b0, acc[0][0]);
            acc[0][1] = MFMA16(a0, b1, acc[0][1]);
            acc[1][0] = MFMA16(a1, b0, acc[1][0]);
            acc[1][1] = MFMA16(a1, b1, acc[1][1]);
        }
        __syncthreads();
    }
    #pragma unroll
    for (int ni = 0; ni < 2; ni++) {
        int colg = col0 + wn * 32 + ni * 16 + m16;
        float bv = bias[colg];
        #pragma unroll
        for (int mi = 0; mi < 2; mi++) {
            #pragma unroll
            for (int r = 0; r < 4; r++) {
                int rowg = row0 + wm * 32 + mi * 16 + quad * 4 + r;
                float v = acc[mi][ni][r] + bv;
                if (GELU) v = 0.5f * v * (1.0f + erff(v * 0.70710678118654752f));
                if (OUT_BF16) ((unsigned short*)Cp)[(size_t)rowg * N + colg] = f2b(v);
                else          ((float*)Cp)[(size_t)rowg * N + colg] = v;
            }
        }
    }
}

// ---------------- MFMA fused flash-style disentangled attention (unchanged) ----------------
__global__ __launch_bounds__(256) void attn_kernel(
    const unsigned short* __restrict__ Q, const unsigned short* __restrict__ K,
    const unsigned short* __restrict__ V,
    const unsigned short* __restrict__ PK, const unsigned short* __restrict__ PQ,
    const int* __restrict__ am, unsigned short* __restrict__ ctx) {
    __shared__ unsigned short Qs[32][72], Ks[32][72];
    __shared__ unsigned short PKw[64][72], PQw[64][72];
    __shared__ unsigned short Vt[64][40];     // [d][kk]
    __shared__ unsigned short Pls[32][40];    // [q][kk] bf16 probs
    __shared__ float Afs[32][65];             // [q][j]  stride 65
    __shared__ float Bfs[32][66];             // [k][j]  stride 66 (banded gather de-conflict)
    __shared__ float Scomb[32][33];
    __shared__ float mrow[32], lrow[32], arow[32];
    __shared__ int mkk[32], mq[32];

    int bh = blockIdx.y, b = bh >> 3, hh = bh & 7;
    int q0 = blockIdx.x * 32;
    int tid = threadIdx.x;
    int lane = tid & 63, wave = tid >> 6;
    int quad = lane >> 4, m16 = lane & 15;
    int qt = wave >> 1, kt = wave & 1;        // S-quadrant assignment
    const float inv_scale = 0.07216878364870323f; // 1/sqrt(192)

    {   // Q tile 32x64 (once)
        int r = tid >> 3, c = (tid & 7) * 8;
        *(uint4*)&Qs[r][c] = *(const uint4*)(Q + (size_t)(b * SEQ + q0 + r) * HID + hh * HEAD + c);
        if (tid < 32) { mrow[tid] = NEG_BIG; lrow[tid] = 0.0f; mq[tid] = am[b * SEQ + q0 + tid]; }
    }
    floatx4 accO[2];
    accO[0] = (floatx4){0.f, 0.f, 0.f, 0.f};
    accO[1] = (floatx4){0.f, 0.f, 0.f, 0.f};

    for (int k0 = 0; k0 < SEQ; k0 += 32) {
        __syncthreads();   // prior PV / gather reads complete before restaging
        {   // stage K (rows), V (transposed), PKw/PQw window
            int r = tid >> 3, c = (tid & 7) * 8;
            *(uint4*)&Ks[r][c] = *(const uint4*)(K + (size_t)(b * SEQ + k0 + r) * HID + hh * HEAD + c);
            uint4 vv = *(const uint4*)(V + (size_t)(b * SEQ + k0 + r) * HID + hh * HEAD + c);
            unsigned short* vp = (unsigned short*)&vv;
            #pragma unroll
            for (int j = 0; j < 8; j++) Vt[c + j][r] = vp[j];
            int d0 = q0 - k0 + 481;   // window base in [1,961]
            #pragma unroll
            for (int i = 0; i < 2; i++) {
                int rr = r + i * 32;
                int row = d0 + rr; row = row > 1023 ? 1023 : row;  // row 63 pad never gathered
                *(uint4*)&PKw[rr][c] = *(const uint4*)(PK + (size_t)row * HID + hh * HEAD + c);
                *(uint4*)&PQw[rr][c] = *(const uint4*)(PQ + (size_t)row * HID + hh * HEAD + c);
            }
            if (tid < 32) mkk[tid] = am[b * SEQ + k0 + tid];
        }
        __syncthreads();

        // ---- MFMA phase: S quadrant + A columns + Bw columns ----
        floatx4 accA0 = (floatx4){0.f,0.f,0.f,0.f}, accA1 = (floatx4){0.f,0.f,0.f,0.f};
        floatx4 accB0 = (floatx4){0.f,0.f,0.f,0.f}, accB1 = (floatx4){0.f,0.f,0.f,0.f};
        floatx4 accS  = (floatx4){0.f,0.f,0.f,0.f};
        #pragma unroll
        for (int ks = 0; ks < 2; ks++) {
            int co = ks * 32 + quad * 8;
            bf16x8 qf0 = *(const bf16x8*)&Qs[m16][co];
            bf16x8 qf1 = *(const bf16x8*)&Qs[16 + m16][co];
            bf16x8 kf0 = *(const bf16x8*)&Ks[m16][co];
            bf16x8 kf1 = *(const bf16x8*)&Ks[16 + m16][co];
            bf16x8 pkf = *(const bf16x8*)&PKw[wave * 16 + m16][co];
            bf16x8 pqf = *(const bf16x8*)&PQw[wave * 16 + m16][co];
            accA0 = MFMA16(qf0, pkf, accA0);
            accA1 = MFMA16(qf1, pkf, accA1);
            accB0 = MFMA16(kf0, pqf, accB0);
            accB1 = MFMA16(kf1, pqf, accB1);
            accS  = MFMA16(qt ? qf1 : qf0, kt ? kf1 : kf0, accS);
        }
        #pragma unroll
        for (int r = 0; r < 4; r++) {   // D: row = quad*4+r, col = wave*16+m16
            Afs[quad * 4 + r][wave * 16 + m16]      = accA0[r];
            Afs[16 + quad * 4 + r][wave * 16 + m16] = accA1[r];
            Bfs[quad * 4 + r][wave * 16 + m16]      = accB0[r];
            Bfs[16 + quad * 4 + r][wave * 16 + m16] = accB1[r];
        }
        __syncthreads();

        {   // combine: scores + banded gather
            int kc = kt * 16 + m16;
            #pragma unroll
            for (int r = 0; r < 4; r++) {
                int qq = qt * 16 + quad * 4 + r;
                int j = qq - kc + 31;            // in [0,62]
                Scomb[qq][kc] = (accS[r] + Afs[qq][j] + Bfs[kc][j]) * inv_scale;
            }
        }
        __syncthreads();

        {   // online softmax: row r, 4 cols/thread, 8 threads/row; P rounded to bf16, l from rounded p
            int r = tid >> 3, cg = (tid & 7) * 4;
            float sv[4]; float tmax = NEG_BIG;
            #pragma unroll
            for (int j = 0; j < 4; j++) {
                sv[j] = mkk[cg + j] ? Scomb[r][cg + j] : NEG_BIG;
                tmax = fmaxf(tmax, sv[j]);
            }
            tmax = fmaxf(tmax, __shfl_xor(tmax, 1));
            tmax = fmaxf(tmax, __shfl_xor(tmax, 2));
            tmax = fmaxf(tmax, __shfl_xor(tmax, 4));
            float mold = mrow[r];
            float mnew = fmaxf(mold, tmax);
            float psum = 0.0f;
            #pragma unroll
            for (int j = 0; j < 4; j++) {
                float p = (sv[j] > -1.5e38f) ? __expf(sv[j] - mnew) : 0.0f;
                unsigned short pb = f2b(p);
                Pls[r][cg + j] = pb;
                psum += b2f(pb);                 // consistent with PV operand
            }
            psum += __shfl_xor(psum, 1);
            psum += __shfl_xor(psum, 2);
            psum += __shfl_xor(psum, 4);
            if ((tid & 7) == 0) {
                float alpha = __expf(mold - mnew);
                mrow[r] = mnew;
                lrow[r] = lrow[r] * alpha + psum;
                arow[r] = alpha;
            }
        }
        __syncthreads();

        {   // O rescale + PV MFMA (wave owns d-cols wave*16+m16)
            #pragma unroll
            for (int q2 = 0; q2 < 2; q2++) {
                #pragma unroll
                for (int r = 0; r < 4; r++) accO[q2][r] *= arow[q2 * 16 + quad * 4 + r];
            }
            bf16x8 pf0 = *(const bf16x8*)&Pls[m16][quad * 8];
            bf16x8 pf1 = *(const bf16x8*)&Pls[16 + m16][quad * 8];
            bf16x8 vf  = *(const bf16x8*)&Vt[wave * 16 + m16][quad * 8];
            accO[0] = MFMA16(pf0, vf, accO[0]);
            accO[1] = MFMA16(pf1, vf, accO[1]);
        }
    }
    __syncthreads();
    // epilogue: O[q][d] / l, query mask, write bf16 ctx
    #pragma unroll
    for (int q2 = 0; q2 < 2; q2++) {
        #pragma unroll
        for (int r = 0; r < 4; r++) {
            int qq = q2 * 16 + quad * 4 + r;
            float l = lrow[qq];
            float inv = l > 0.0f ? 1.0f / l : 0.0f;
            inv *= (float)mq[qq];
            ctx[(size_t)(b * SEQ + q0 + qq) * HID + hh * HEAD + wave * 16 + m16] = f2b(accO[q2][r] * inv);
        }
    }
}

// ---------------- output copy / classifier (fp32 out) ----------------
__global__ void copy_f_kernel(const float* __restrict__ in, float* __restrict__ out, int n) {
    int i = blockIdx.x * 256 + threadIdx.x;
    if (i < n) out[i] = in[i];
}
__global__ void cls_kernel(const float* __restrict__ h, const float* __restrict__ cls_w,
                           const float* __restrict__ cls_b, float* __restrict__ out) {
    int t = blockIdx.x, v = threadIdx.x;
    if (v < VOCAB) {
        const float* hr = h + (size_t)t * HID;
        const float* wr = cls_w + (size_t)v * HID;
        float acc = cls_b[v];
        for (int d = 0; d < HID; d++) acc += hr[d] * wr[d];
        out[t * VOCAB + v] = acc;
    }
}

extern "C" void kernel_launch(void* const* d_in, const int* in_sizes, int n_in,
                              void* d_out, int out_size, void* d_ws, size_t ws_size,
                              hipStream_t stream) {
    const int* x     = (const int*)d_in[0];
    const int* am    = (const int*)d_in[1];
    const float* word_emb = (const float*)d_in[2];
    const float* emb_g    = (const float*)d_in[3];
    const float* emb_b    = (const float*)d_in[4];
    const float* rel_emb  = (const float*)d_in[5];
    const float* Wq  = (const float*)d_in[6];  const float* bq  = (const float*)d_in[7];
    const float* Wk  = (const float*)d_in[8];  const float* bk  = (const float*)d_in[9];
    const float* Wv  = (const float*)d_in[10]; const float* bv  = (const float*)d_in[11];
    const float* Wpk = (const float*)d_in[12]; const float* bpk = (const float*)d_in[13];
    const float* Wpq = (const float*)d_in[14]; const float* bpq = (const float*)d_in[15];
    const float* Wo  = (const float*)d_in[16]; const float* bo  = (const float*)d_in[17];
    const float* ln1g = (const float*)d_in[18]; const float* ln1b = (const float*)d_in[19];
    const float* W1  = (const float*)d_in[20]; const float* b1  = (const float*)d_in[21];
    const float* W2  = (const float*)d_in[22]; const float* b2  = (const float*)d_in[23];
    const float* ln2g = (const float*)d_in[24]; const float* ln2b = (const float*)d_in[25];
    const float* cls_w = (const float*)d_in[26]; const float* cls_b = (const float*)d_in[27];

    char* wsb = (char*)d_ws;
    const size_t NEED_BIG = 107u << 20;   // 23 MB activations + 84 MB bf16 weights

    if (ws_size >= NEED_BIG) {
        // ---- big-workspace path: preconverted transposed bf16 weights ----
        float* h  = (float*)wsb;                                      // 4 MB
        float* t1 = (float*)(wsb + (4u << 20));                       // 4 MB (split-K part 0)
        // t2 = t1 + TOK*HID lives at 8 MB (split-K part 1, addressed inside gemm_bt)
        float* t2 = (float*)(wsb + (8u << 20));                       // 4 MB
        unsigned short* qb   = (unsigned short*)(wsb + (12u << 20));  // 2 MB
        unsigned short* kb   = (unsigned short*)(wsb + (14u << 20));  // 2 MB
        unsigned short* vb   = (unsigned short*)(wsb + (16u << 20));  // 2 MB
        unsigned short* pkb  = (unsigned short*)(wsb + (18u << 20));  // 1 MB
        unsigned short* pqb  = (unsigned short*)(wsb + (19u << 20));  // 1 MB
        unsigned short* relb = (unsigned short*)(wsb + (20u << 20));  // 1 MB
        unsigned short* hb   = (unsigned short*)(wsb + (21u << 20));  // 2 MB
        unsigned short* ctx  = hb;   // alias: hb dead between attn and add_ln1
        unsigned short* ffb  = qb;   // alias: qb..pqb (8 MB) dead by FF1
        unsigned short* Wqt  = (unsigned short*)(wsb + (23u << 20));  // 6x6 MB: q,k,v,pk,pq,o
        unsigned short* W1t  = (unsigned short*)(wsb + (59u << 20));  // 24 MB
        unsigned short* W2t  = (unsigned short*)(wsb + (83u << 20));  // 24 MB

        const size_t M512 = (size_t)HID * HID;   // elements per 512x512 matrix

        tcvt6_kernel<<<dim3(16, 16, 72), dim3(32, 8), 0, stream>>>(Wq, Wk, Wv, Wpk, Wpq, Wo, Wqt);
        tcvt_kernel<<<dim3(64, 16, 12), dim3(32, 8), 0, stream>>>(W1, W1t, HID, FFDIM);
        tcvt_kernel<<<dim3(16, 64, 12), dim3(32, 8), 0, stream>>>(W2, W2t, FFDIM, HID);
        cvt_rel_kernel<<<dim3(SPAN2 * HID / 1024), dim3(256), 0, stream>>>(rel_emb, relb);
        embed_ln_kernel<<<dim3(TOK), dim3(256), 0, stream>>>(x, am, word_emb, emb_g, emb_b, h, hb);

        for (int l = 0; l < NLAYER; l++) {
            qkvp_gemm<<<dim3(1024), dim3(256), 0, stream>>>(
                hb, relb,
                Wqt + (size_t)(0 * NLAYER + l) * M512, Wqt + (size_t)(1 * NLAYER + l) * M512,
                Wqt + (size_t)(2 * NLAYER + l) * M512, Wqt + (size_t)(3 * NLAYER + l) * M512,
                Wqt + (size_t)(4 * NLAYER + l) * M512,
                bq + l * HID, bk + l * HID, bv + l * HID, bpk + l * HID, bpq + l * HID,
                qb, kb, vb, pkb, pqb);

            attn_kernel<<<dim3(SEQ / 32, BATCH * NHEAD), dim3(256), 0, stream>>>(
                qb, kb, vb, pkb, pqb, am, ctx);

            gemm_bt<false, false, 2><<<dim3(HID / 64, TOK / 64, 2), dim3(256), 0, stream>>>(
                ctx, Wqt + (size_t)(5 * NLAYER + l) * M512, bo + l * HID, t1, HID, HID);
            add_ln2_kernel<<<dim3(TOK), dim3(256), 0, stream>>>(t1, t2, ln1g + l * HID, ln1b + l * HID, h, hb);

            gemm_bt<true, true, 1><<<dim3(FFDIM / 64, TOK / 64, 1), dim3(256), 0, stream>>>(
                hb, W1t + (size_t)l * HID * FFDIM, b1 + l * FFDIM, ffb, FFDIM, HID);
            gemm_bt<false, false, 2><<<dim3(HID / 64, TOK / 64, 2), dim3(256), 0, stream>>>(
                ffb, W2t + (size_t)l * HID * FFDIM, b2 + l * HID, t1, HID, FFDIM);
            add_ln2_kernel<<<dim3(TOK), dim3(256), 0, stream>>>(t1, t2, ln2g + l * HID, ln2b + l * HID, h, hb);
        }

        float* out_f = (float*)d_out;
        copy_f_kernel<<<dim3(TOK * HID / 256), dim3(256), 0, stream>>>(h, out_f, TOK * HID);
        cls_kernel<<<dim3(TOK), dim3(32), 0, stream>>>(h, cls_w, cls_b, out_f + TOK * HID);
        return;
    }

    // ---- fallback path: baseline 19 MB layout, inline fp32->bf16 weight conversion ----
    const size_t NEEDED = 19u << 20;
    if (ws_size < NEEDED) return;
    float* h  = (float*)wsb;                                     // 4 MB
    float* t1 = (float*)(wsb + (4u << 20));                      // 4 MB
    unsigned short* qb   = (unsigned short*)(wsb + (8u << 20));  // 2 MB
    unsigned short* kb   = qb  + (1u << 20);                     // 2 MB
    unsigned short* vb   = kb  + (1u << 20);                     // 2 MB
    unsigned short* pkb  = vb  + (1u << 20);                     // 1 MB
    unsigned short* pqb  = pkb + (1u << 19);                     // 1 MB
    unsigned short* relb = (unsigned short*)(wsb + (16u << 20)); // 1 MB
    unsigned short* hb   = (unsigned short*)(wsb + (17u << 20)); // 2 MB
    unsigned short* ctx  = hb;   // alias: hb dead between V-GEMM and add_ln1
    unsigned short* ffb  = qb;   // alias: q..pq dead by FF1

    cvt_rel_kernel<<<dim3(SPAN2 * HID / 1024), dim3(256), 0, stream>>>(rel_emb, relb);
    embed_ln_kernel<<<dim3(TOK), dim3(256), 0, stream>>>(x, am, word_emb, emb_g, emb_b, h, hb);

    for (int l = 0; l < NLAYER; l++) {
        const float* Wq_l = Wq + (size_t)l * HID * HID;
        const float* Wk_l = Wk + (size_t)l * HID * HID;
        const float* Wv_l = Wv + (size_t)l * HID * HID;
        const float* Wo_l = Wo + (size_t)l * HID * HID;
        const float* Wpk_l = Wpk + (size_t)l * HID * HID;
        const float* Wpq_l = Wpq + (size_t)l * HID * HID;
        const float* W1_l = W1 + (size_t)l * HID * FFDIM;
        const float* W2_l = W2 + (size_t)l * FFDIM * HID;

        mfma_gemm<true,  false><<<dim3(HID/64, TOK/64),   dim3(256), 0, stream>>>(hb,   Wq_l,  bq + l*HID,  qb,  HID, HID);
        mfma_gemm<true,  false><<<dim3(HID/64, TOK/64),   dim3(256), 0, stream>>>(hb,   Wk_l,  bk + l*HID,  kb,  HID, HID);
        mfma_gemm<true,  false><<<dim3(HID/64, TOK/64),   dim3(256), 0, stream>>>(hb,   Wv_l,  bv + l*HID,  vb,  HID, HID);
        mfma_gemm<true,  false><<<dim3(HID/64, SPAN2/64), dim3(256), 0, stream>>>(relb, Wpk_l, bpk + l*HID, pkb, HID, HID);
        mfma_gemm<true,  false><<<dim3(HID/64, SPAN2/64), dim3(256), 0, stream>>>(relb, Wpq_l, bpq + l*HID, pqb, HID, HID);

        attn_kernel<<<dim3(SEQ/32, BATCH*NHEAD), dim3(256), 0, stream>>>(qb, kb, vb, pkb, pqb, am, ctx);

        mfma_gemm<false, false><<<dim3(HID/64, TOK/64),   dim3(256), 0, stream>>>(ctx,  Wo_l,  bo + l*HID,  t1,  HID, HID);
        add_ln_kernel<<<dim3(TOK), dim3(256), 0, stream>>>(t1, ln1g + l*HID, ln1b + l*HID, h, hb);

        mfma_gemm<true,  true ><<<dim3(FFDIM/64, TOK/64), dim3(256), 0, stream>>>(hb,   W1_l,  b1 + l*FFDIM, ffb, FFDIM, HID);
        mfma_gemm<false, false><<<dim3(HID/64, TOK/64),   dim3(256), 0, stream>>>(ffb,  W2_l,  b2 + l*HID,  t1,  HID, FFDIM);
        add_ln_kernel<<<dim3(TOK), dim3(256), 0, stream>>>(t1, ln2g + l*HID, ln2b + l*HID, h, hb);
    }

    float* out_f = (float*)d_out;
    copy_f_kernel<<<dim3(TOK*HID/256), dim3(256), 0, stream>>>(h, out_f, TOK*HID);
    cls_kernel<<<dim3(TOK), dim3(32), 0, stream>>>(h, cls_w, cls_b, out_f + TOK*HID);
}

// Round 2
// 1455.529 us; speedup vs baseline: 1.6197x; 1.0357x over previous
//
#include <hip/hip_runtime.h>
#include <hip/hip_bf16.h>

// Model dims (fixed by the reference)
#define BATCH  4
#define SEQ    512
#define TOK    (BATCH*SEQ)     // 2048
#define HID    512
#define NHEAD  8
#define HEAD   64
#define FFDIM  2048
#define NLAYER 12
#define SPAN2  1024            // 2*SPAN
#define VOCAB  25
#define LNEPS  1e-7f
#define NEG_BIG -3.0e38f

typedef __attribute__((ext_vector_type(8))) short bf16x8;   // 8 bf16 = 4 VGPRs
typedef __attribute__((ext_vector_type(4))) float floatx4;

#define MFMA16(a, b, c) __builtin_amdgcn_mfma_f32_16x16x32_bf16((a), (b), (c), 0, 0, 0)

__device__ __forceinline__ float b2f(unsigned short u) {
    return __uint_as_float(((unsigned int)u) << 16);
}
__device__ __forceinline__ unsigned short f2b(float f) {
    __hip_bfloat16 h = __float2bfloat16(f);
    return *(unsigned short*)&h;
}

// ---------------- block reductions (blockDim = 256, 1-D) ----------------
__device__ __forceinline__ float block_reduce_sum(float v, float* red) {
    int tid = threadIdx.x;
    red[tid] = v; __syncthreads();
    for (int s = 128; s > 0; s >>= 1) { if (tid < s) red[tid] += red[tid + s]; __syncthreads(); }
    float r = red[0]; __syncthreads();
    return r;
}

// ---------------- embedding gather + LN + mask (writes fp32 h and bf16 hb) ----------------
__global__ void embed_ln_kernel(const int* __restrict__ x, const int* __restrict__ am,
                                const float* __restrict__ word_emb,
                                const float* __restrict__ g, const float* __restrict__ bb,
                                float* __restrict__ h, unsigned short* __restrict__ hb) {
    __shared__ float red[256];
    int t = blockIdx.x, tid = threadIdx.x;
    const float* we = word_emb + (size_t)x[t] * HID;
    float v1 = we[tid], v2 = we[tid + 256];
    float mean = block_reduce_sum(v1 + v2, red) * (1.0f / HID);
    float d1 = v1 - mean, d2 = v2 - mean;
    float var = block_reduce_sum(d1 * d1 + d2 * d2, red) * (1.0f / HID);
    float rstd = rsqrtf(var + LNEPS);
    float maskf = (float)am[t];
    size_t base = (size_t)t * HID;
    float o1 = (d1 * rstd * g[tid]       + bb[tid])       * maskf;
    float o2 = (d2 * rstd * g[tid + 256] + bb[tid + 256]) * maskf;
    h[base + tid] = o1;        h[base + tid + 256] = o2;
    hb[base + tid] = f2b(o1);  hb[base + tid + 256] = f2b(o2);
}

// ---------------- residual add + LN, single tmp (fallback path) ----------------
__global__ void add_ln_kernel(const float* __restrict__ tmp,
                              const float* __restrict__ g, const float* __restrict__ bb,
                              float* __restrict__ h, unsigned short* __restrict__ hb) {
    __shared__ float red[256];
    int t = blockIdx.x, tid = threadIdx.x;
    size_t base = (size_t)t * HID;
    float v1 = tmp[base + tid] + h[base + tid];
    float v2 = tmp[base + tid + 256] + h[base + tid + 256];
    float mean = block_reduce_sum(v1 + v2, red) * (1.0f / HID);
    float d1 = v1 - mean, d2 = v2 - mean;
    float var = block_reduce_sum(d1 * d1 + d2 * d2, red) * (1.0f / HID);
    float rstd = rsqrtf(var + LNEPS);
    float o1 = d1 * rstd * g[tid]       + bb[tid];
    float o2 = d2 * rstd * g[tid + 256] + bb[tid + 256];
    h[base + tid] = o1;        h[base + tid + 256] = o2;
    hb[base + tid] = f2b(o1);  hb[base + tid + 256] = f2b(o2);
}

// ---------------- residual add + LN, two split-K partials ----------------
__global__ void add_ln2_kernel(const float* __restrict__ t1a, const float* __restrict__ t1b,
                               const float* __restrict__ g, const float* __restrict__ bb,
                               float* __restrict__ h, unsigned short* __restrict__ hb) {
    __shared__ float red[256];
    int t = blockIdx.x, tid = threadIdx.x;
    size_t base = (size_t)t * HID;
    float v1 = t1a[base + tid] + t1b[base + tid] + h[base + tid];
    float v2 = t1a[base + tid + 256] + t1b[base + tid + 256] + h[base + tid + 256];
    float mean = block_reduce_sum(v1 + v2, red) * (1.0f / HID);
    float d1 = v1 - mean, d2 = v2 - mean;
    float var = block_reduce_sum(d1 * d1 + d2 * d2, red) * (1.0f / HID);
    float rstd = rsqrtf(var + LNEPS);
    float o1 = d1 * rstd * g[tid]       + bb[tid];
    float o2 = d2 * rstd * g[tid + 256] + bb[tid + 256];
    h[base + tid] = o1;        h[base + tid + 256] = o2;
    hb[base + tid] = f2b(o1);  hb[base + tid + 256] = f2b(o2);
}

// ---------------- fp32 -> bf16 convert (rel_emb, n multiple of 1024) ----------------
__global__ void cvt_rel_kernel(const float* __restrict__ in, unsigned short* __restrict__ out) {
    int i = (blockIdx.x * 256 + threadIdx.x) * 4;
    float4 v = *(const float4*)(in + i);
    out[i] = f2b(v.x); out[i+1] = f2b(v.y); out[i+2] = f2b(v.z); out[i+3] = f2b(v.w);
}

// ---------------- transpose+convert: W[K][N] fp32 -> Wt[N][K] bf16, blockIdx.z = layer ----------------
__global__ void tcvt_kernel(const float* __restrict__ in, unsigned short* __restrict__ out,
                            int K, int N) {
    __shared__ float tile[32][33];
    int l = blockIdx.z;
    const float* ip = in + (size_t)l * K * N;
    unsigned short* op = out + (size_t)l * K * N;
    int kb = blockIdx.y * 32, nb = blockIdx.x * 32;
    int tx = threadIdx.x, ty = threadIdx.y;   // block (32,8)
    #pragma unroll
    for (int i = 0; i < 32; i += 8) tile[ty + i][tx] = ip[(size_t)(kb + ty + i) * N + nb + tx];
    __syncthreads();
    #pragma unroll
    for (int i = 0; i < 32; i += 8) op[(size_t)(nb + ty + i) * K + kb + tx] = f2b(tile[tx][ty + i]);
}

// six [12][512][512] weight arrays in one launch; z = l*6 + w; out contiguous [w][l][512][512]
__global__ void tcvt6_kernel(const float* __restrict__ Wq, const float* __restrict__ Wk,
                             const float* __restrict__ Wv, const float* __restrict__ Wpk,
                             const float* __restrict__ Wpq, const float* __restrict__ Wo,
                             unsigned short* __restrict__ out) {
    __shared__ float tile[32][33];
    int z = blockIdx.z, l = z / 6, w = z - l * 6;
    const float* src = w == 0 ? Wq : w == 1 ? Wk : w == 2 ? Wv : w == 3 ? Wpk : w == 4 ? Wpq : Wo;
    const float* ip = src + (size_t)l * HID * HID;
    unsigned short* op = out + ((size_t)w * NLAYER + l) * HID * HID;
    int kb = blockIdx.y * 32, nb = blockIdx.x * 32;
    int tx = threadIdx.x, ty = threadIdx.y;
    #pragma unroll
    for (int i = 0; i < 32; i += 8) tile[ty + i][tx] = ip[(size_t)(kb + ty + i) * HID + nb + tx];
    __syncthreads();
    #pragma unroll
    for (int i = 0; i < 32; i += 8) op[(size_t)(nb + ty + i) * HID + kb + tx] = f2b(tile[tx][ty + i]);
}

// ---------------- shared 64x64 tile core: A[M][K] bf16 x Bt[N][K] bf16 ----------------
__device__ __forceinline__ void gemm_tile_bt(
    const unsigned short* __restrict__ A, const unsigned short* __restrict__ Bt,
    int row0, int col0, int K, int kbeg, int kend,
    floatx4 (&acc)[2][2], unsigned short (&As)[64][72], unsigned short (&Bs)[64][72]) {
    int tid = threadIdx.x;
    int lane = tid & 63, wid = tid >> 6;
    int wm = wid >> 1, wn = wid & 1;
    int m16 = lane & 15, quad = lane >> 4;
    int sr = tid >> 2, sc = (tid & 3) << 4;          // staging: row, 16 bf16 cols
    const unsigned short* Ag = A + (size_t)(row0 + sr) * K + sc;
    const unsigned short* Bg = Bt + (size_t)(col0 + sr) * K + sc;
    for (int k0 = kbeg; k0 < kend; k0 += 64) {
        uint4 av0 = *(const uint4*)(Ag + k0);
        uint4 av1 = *(const uint4*)(Ag + k0 + 8);
        uint4 bv0 = *(const uint4*)(Bg + k0);
        uint4 bv1 = *(const uint4*)(Bg + k0 + 8);
        *(uint4*)&As[sr][sc]     = av0;
        *(uint4*)&As[sr][sc + 8] = av1;
        *(uint4*)&Bs[sr][sc]     = bv0;
        *(uint4*)&Bs[sr][sc + 8] = bv1;
        __syncthreads();
        #pragma unroll
        for (int kk = 0; kk < 2; kk++) {
            bf16x8 a0 = *(const bf16x8*)&As[wm * 32 + m16][kk * 32 + quad * 8];
            bf16x8 a1 = *(const bf16x8*)&As[wm * 32 + 16 + m16][kk * 32 + quad * 8];
            bf16x8 b0 = *(const bf16x8*)&Bs[wn * 32 + m16][kk * 32 + quad * 8];
            bf16x8 b1 = *(const bf16x8*)&Bs[wn * 32 + 16 + m16][kk * 32 + quad * 8];
            acc[0][0] = MFMA16(a0, b0, acc[0][0]);
            acc[0][1] = MFMA16(a0, b1, acc[0][1]);
            acc[1][0] = MFMA16(a1, b0, acc[1][0]);
            acc[1][1] = MFMA16(a1, b1, acc[1][1]);
        }
        __syncthreads();
    }
}

// ---------------- generic bf16-weight GEMM, optional split-K over blockIdx.z ----------------
template<bool OUT_BF16, bool GELU, int SPLITK>
__global__ __launch_bounds__(256) void gemm_bt(
    const unsigned short* __restrict__ A, const unsigned short* __restrict__ Bt,
    const float* __restrict__ bias, void* __restrict__ Cp, int N, int K) {
    __shared__ unsigned short As[64][72], Bs[64][72];
    int row0 = blockIdx.y * 64, col0 = blockIdx.x * 64;
    int kseg = K / SPLITK;
    int kbeg = kseg * blockIdx.z, kend = kbeg + kseg;
    floatx4 acc[2][2];
    #pragma unroll
    for (int mi = 0; mi < 2; mi++)
        #pragma unroll
        for (int ni = 0; ni < 2; ni++) acc[mi][ni] = (floatx4){0.f, 0.f, 0.f, 0.f};
    gemm_tile_bt(A, Bt, row0, col0, K, kbeg, kend, acc, As, Bs);

    int tid = threadIdx.x, lane = tid & 63, wid = tid >> 6;
    int wm = wid >> 1, wn = wid & 1, m16 = lane & 15, quad = lane >> 4;
    size_t outoff = (size_t)blockIdx.z * (size_t)(gridDim.y << 6) * N;
    #pragma unroll
    for (int ni = 0; ni < 2; ni++) {
        int colg = col0 + wn * 32 + ni * 16 + m16;
        float bval = (SPLITK == 1 || blockIdx.z == 0) ? bias[colg] : 0.0f;
        #pragma unroll
        for (int mi = 0; mi < 2; mi++) {
            #pragma unroll
            for (int r = 0; r < 4; r++) {
                int rowg = row0 + wm * 32 + mi * 16 + quad * 4 + r;
                float v = acc[mi][ni][r] + bval;
                if (GELU) v = 0.5f * v * (1.0f + erff(v * 0.70710678118654752f));
                if (OUT_BF16) ((unsigned short*)Cp)[(size_t)rowg * N + colg] = f2b(v);
                else          ((float*)Cp)[outoff + (size_t)rowg * N + colg] = v;
            }
        }
    }
}

// ---------------- fused Q,K,V,Pk,Pq projections: 1024 workgroups, one launch ----------------
__global__ __launch_bounds__(256) void qkvp_gemm(
    const unsigned short* __restrict__ hb, const unsigned short* __restrict__ relb,
    const unsigned short* __restrict__ Wqt, const unsigned short* __restrict__ Wkt,
    const unsigned short* __restrict__ Wvt, const unsigned short* __restrict__ Wpkt,
    const unsigned short* __restrict__ Wpqt,
    const float* __restrict__ bq, const float* __restrict__ bk, const float* __restrict__ bv,
    const float* __restrict__ bpk, const float* __restrict__ bpq,
    unsigned short* __restrict__ qb, unsigned short* __restrict__ kb,
    unsigned short* __restrict__ vb, unsigned short* __restrict__ pkb,
    unsigned short* __restrict__ pqb) {
    __shared__ unsigned short As[64][72], Bs[64][72];
    int gid = blockIdx.x;
    const unsigned short* A; const unsigned short* Bt; const float* bias; unsigned short* C;
    int trow, tcol;
    if (gid < 768) {                       // Q,K,V: M=2048 -> 32x8 tiles each
        int op = gid >> 8, t = gid & 255;
        trow = t >> 3; tcol = t & 7;
        A = hb;
        Bt   = op == 0 ? Wqt : op == 1 ? Wkt : Wvt;
        bias = op == 0 ? bq  : op == 1 ? bk  : bv;
        C    = op == 0 ? qb  : op == 1 ? kb  : vb;
    } else {                               // Pk,Pq: M=1024 -> 16x8 tiles each
        int g = gid - 768, op = g >> 7, t = g & 127;
        trow = t >> 3; tcol = t & 7;
        A = relb;
        Bt   = op ? Wpqt : Wpkt;
        bias = op ? bpq  : bpk;
        C    = op ? pqb  : pkb;
    }
    floatx4 acc[2][2];
    #pragma unroll
    for (int mi = 0; mi < 2; mi++)
        #pragma unroll
        for (int ni = 0; ni < 2; ni++) acc[mi][ni] = (floatx4){0.f, 0.f, 0.f, 0.f};
    gemm_tile_bt(A, Bt, trow * 64, tcol * 64, HID, 0, HID, acc, As, Bs);

    int tid = threadIdx.x, lane = tid & 63, wid = tid >> 6;
    int wm = wid >> 1, wn = wid & 1, m16 = lane & 15, quad = lane >> 4;
    #pragma unroll
    for (int ni = 0; ni < 2; ni++) {
        int colg = tcol * 64 + wn * 32 + ni * 16 + m16;
        float bval = bias[colg];
        #pragma unroll
        for (int mi = 0; mi < 2; mi++) {
            #pragma unroll
            for (int r = 0; r < 4; r++) {
                int rowg = trow * 64 + wm * 32 + mi * 16 + quad * 4 + r;
                C[(size_t)rowg * HID + colg] = f2b(acc[mi][ni][r] + bval);
            }
        }
    }
}

// ---------------- fallback MFMA GEMM: B fp32 inline-converted (baseline path) ----------------
template<bool OUT_BF16, bool GELU>
__global__ __launch_bounds__(256) void mfma_gemm(
    const unsigned short* __restrict__ A, const float* __restrict__ B,
    const float* __restrict__ bias, void* __restrict__ Cp, int N, int K) {
    __shared__ unsigned short As[64][72];   // [m][k]
    __shared__ unsigned short Bs[64][72];   // [n][k]
    int tid = threadIdx.x;
    int lane = tid & 63, wid = tid >> 6;
    int wm = wid >> 1, wn = wid & 1;
    int row0 = blockIdx.y * 64, col0 = blockIdx.x * 64;
    int m16 = lane & 15, quad = lane >> 4;

    int ar = tid >> 2, ac = (tid & 3) << 4;
    int bk = (tid >> 3) << 1, bn = (tid & 7) << 3;

    const unsigned short* Ag = A + (size_t)(row0 + ar) * K + ac;
    const float* Bg = B + (size_t)bk * N + col0 + bn;

    floatx4 acc[2][2];
    #pragma unroll
    for (int mi = 0; mi < 2; mi++)
        #pragma unroll
        for (int ni = 0; ni < 2; ni++) acc[mi][ni] = (floatx4){0.f, 0.f, 0.f, 0.f};

    for (int k0 = 0; k0 < K; k0 += 64) {
        uint4 av0 = *(const uint4*)(Ag + k0);
        uint4 av1 = *(const uint4*)(Ag + k0 + 8);
        const float* br0 = Bg + (size_t)k0 * N;
        const float* br1 = br0 + N;
        float4 b00 = *(const float4*)br0, b01 = *(const float4*)(br0 + 4);
        float4 b10 = *(const float4*)br1, b11 = *(const float4*)(br1 + 4);
        *(uint4*)&As[ar][ac] = av0;
        *(uint4*)&As[ar][ac + 8] = av1;
        float lo[8] = {b00.x, b00.y, b00.z, b00.w, b01.x, b01.y, b01.z, b01.w};
        float hi[8] = {b10.x, b10.y, b10.z, b10.w, b11.x, b11.y, b11.z, b11.w};
        #pragma unroll
        for (int i = 0; i < 8; i++) {
            unsigned int p = (unsigned int)f2b(lo[i]) | ((unsigned int)f2b(hi[i]) << 16);
            *(unsigned int*)&Bs[bn + i][bk] = p;
        }
        __syncthreads();
        #pragma unroll
        for (int kk = 0; kk < 2; kk++) {
            bf16x8 a0 = *(const bf16x8*)&As[wm * 32 + m16][kk * 32 + quad * 8];
            bf16x8 a1 = *(const bf16x8*)&As[wm * 32 + 16 + m16][kk * 32 + quad * 8];
            bf16x8 b0 = *(const bf16x8*)&Bs[wn * 32 + m16][kk * 32 + quad * 8];
            bf16x8 b1 = *(const bf16x8*)&Bs[wn * 32 + 16 + m16][kk * 32 + quad * 8];
            acc[0][0] = MFMA16(a0, b0, acc[0][0]);
            acc[0][1] = MFMA16(a0, b1, acc[0][1]);
            acc[1][0] = MFMA16(a1, b0, acc[1][0]);
            acc[1][1] = MFMA16(a1, b1, acc[1][1]);
        }
        __syncthreads();
    }
    #pragma unroll
    for (int ni = 0; ni < 2; ni++) {
        int colg = col0 + wn * 32 + ni * 16 + m16;
        float bv = bias[colg];
        #pragma unroll
        for (int mi = 0; mi < 2; mi++) {
            #pragma unroll
            for (int r = 0; r < 4; r++) {
                int rowg = row0 + wm * 32 + mi * 16 + quad * 4 + r;
                float v = acc[mi][ni][r] + bv;
                if (GELU) v = 0.5f * v * (1.0f + erff(v * 0.70710678118654752f));
                if (OUT_BF16) ((unsigned short*)Cp)[(size_t)rowg * N + colg] = f2b(v);
                else          ((float*)Cp)[(size_t)rowg * N + colg] = v;
            }
        }
    }
}

// ---------------- MFMA fused flash-style disentangled attention, v2 ----------------
// 4 waves = 2 q-strips (u) x 2 k-halves (s). Wave owns 16 q rows; online softmax fully
// in registers (rows = quad*4+r, shuffle-reduce over m16 lanes). Per phase: stage K/V
// tiles for BOTH parities (2 barriers), each wave consumes its parity tile with
// wave-local LDS only (Afs/Bfs/Pls). PK/PQ operand fragments are loaded directly from
// global (L2-hot). k-halves merged once at the end (flash split-k merge).
__global__ __launch_bounds__(256, 2) void attn_kernel(
    const unsigned short* __restrict__ Q, const unsigned short* __restrict__ K,
    const unsigned short* __restrict__ V,
    const unsigned short* __restrict__ PK, const unsigned short* __restrict__ PQ,
    const int* __restrict__ am, unsigned short* __restrict__ ctx) {
    __shared__ unsigned short Ks[2][32][72];   // [slot][key][d]
    __shared__ unsigned short Vt[2][64][40];   // [slot][d][key^swz]
    __shared__ float Afs[4][16][49];           // per-wave A band (c2p)
    __shared__ float Bfs[4][32][50];           // per-wave B band (p2c); aliased as mergeO at end
    __shared__ unsigned short Pls[4][16][40];  // per-wave P (bf16)
    __shared__ int mkk[2][32];
    __shared__ float mergeML[2][2][16];        // [strip][m|l][row]

    int bh = blockIdx.y, b = bh >> 3, hh = bh & 7;
    int q0 = blockIdx.x * 32;
    int tid = threadIdx.x;
    int lane = tid & 63, wave = tid >> 6;
    int u = wave >> 1;                 // q-strip
    int s = wave & 1;                  // k-parity
    int quad = lane >> 4, m16 = lane & 15;
    const float inv_scale = 0.07216878364870323f; // 1/sqrt(192)

    // Q fragments in registers (A-operand: row=m16, k=quad*8, 2 chains)
    const unsigned short* qg = Q + (size_t)(b * SEQ + q0 + u * 16 + m16) * HID + hh * HEAD;
    bf16x8 qf0 = *(const bf16x8*)(qg + quad * 8);
    bf16x8 qf1 = *(const bf16x8*)(qg + 32 + quad * 8);

    // staging indices
    int sr = tid >> 3;                 // 0..31 key row
    int sc = (tid & 7) * 8;            // d base
    int vkey = ((sc >> 3) & 3) << 3;   // Vt swizzle key (per-thread const)

    floatx4 accO[4];
    #pragma unroll
    for (int nt = 0; nt < 4; nt++) accO[nt] = (floatx4){0.f, 0.f, 0.f, 0.f};
    float mreg[4] = {NEG_BIG, NEG_BIG, NEG_BIG, NEG_BIG};
    float lreg[4] = {0.f, 0.f, 0.f, 0.f};

    for (int ph = 0; ph < 8; ph++) {
        int t = 2 * ph + s;
        int P0  = q0 - 32 * t + 481;   // pk window base (c2p), rows P0..P0+63 used
        int P20 = 32 * t - q0 + 481;   // pq window base (p2c)
        int Jb  = 16 - 16 * u;         // per-strip pq sub-window base

        // ---- issue PK/PQ operand fragment loads early (global, L2-hot) ----
        bf16x8 pkf[3][2], pqf[3][2];
        #pragma unroll
        for (int nt = 0; nt < 3; nt++) {
            int prow = P0 + 16 * u + nt * 16 + m16;              // <= 992, no clamp
            const unsigned short* pg = PK + (size_t)prow * HID + hh * HEAD + quad * 8;
            pkf[nt][0] = *(const bf16x8*)pg;
            pkf[nt][1] = *(const bf16x8*)(pg + 32);
            int prow2 = P20 + Jb + nt * 16 + m16;
            if (prow2 > 1023) prow2 = 1023;                      // pad row, never gathered
            const unsigned short* pg2 = PQ + (size_t)prow2 * HID + hh * HEAD + quad * 8;
            pqf[nt][0] = *(const bf16x8*)pg2;
            pqf[nt][1] = *(const bf16x8*)(pg2 + 32);
        }

        // ---- stage both parity tiles (K rows, V transposed+swizzled) ----
        #pragma unroll
        for (int sl = 0; sl < 2; sl++) {
            int k0 = ph * 64 + sl * 32;
            const unsigned short* kg = K + (size_t)(b * SEQ + k0 + sr) * HID + hh * HEAD + sc;
            *(uint4*)&Ks[sl][sr][sc] = *(const uint4*)kg;
            uint4 vv = *(const uint4*)(V + (size_t)(b * SEQ + k0 + sr) * HID + hh * HEAD + sc);
            unsigned short* vp = (unsigned short*)&vv;
            #pragma unroll
            for (int j = 0; j < 8; j++) Vt[sl][sc + j][sr ^ vkey] = vp[j];
        }
        if (tid < 64) mkk[tid >> 5][tid & 31] = am[b * SEQ + ph * 64 + tid];
        __syncthreads();

        // ---- S = Q @ K^T (16x32) ----
        floatx4 accS[2];
        accS[0] = (floatx4){0.f, 0.f, 0.f, 0.f};
        accS[1] = (floatx4){0.f, 0.f, 0.f, 0.f};
        #pragma unroll
        for (int n = 0; n < 2; n++) {
            bf16x8 kfa = *(const bf16x8*)&Ks[s][n * 16 + m16][quad * 8];
            bf16x8 kfb = *(const bf16x8*)&Ks[s][n * 16 + m16][32 + quad * 8];
            accS[n] = MFMA16(qf0, kfa, accS[n]);
            accS[n] = MFMA16(qf1, kfb, accS[n]);
        }

        // ---- A = Q @ PKwin^T (16x48), wave-local ----
        {
            floatx4 accA[3];
            #pragma unroll
            for (int nt = 0; nt < 3; nt++) {
                accA[nt] = (floatx4){0.f, 0.f, 0.f, 0.f};
                accA[nt] = MFMA16(qf0, pkf[nt][0], accA[nt]);
                accA[nt] = MFMA16(qf1, pkf[nt][1], accA[nt]);
            }
            #pragma unroll
            for (int nt = 0; nt < 3; nt++)
                #pragma unroll
                for (int r = 0; r < 4; r++)
                    Afs[wave][quad * 4 + r][nt * 16 + m16] = accA[nt][r];
        }

        // ---- B = K @ PQwin^T (32x48 at col offset Jb), wave-local ----
        {
            floatx4 accB[2][3];
            #pragma unroll
            for (int mt = 0; mt < 2; mt++) {
                bf16x8 afa = *(const bf16x8*)&Ks[s][mt * 16 + m16][quad * 8];
                bf16x8 afb = *(const bf16x8*)&Ks[s][mt * 16 + m16][32 + quad * 8];
                #pragma unroll
                for (int nt = 0; nt < 3; nt++) {
                    accB[mt][nt] = (floatx4){0.f, 0.f, 0.f, 0.f};
                    accB[mt][nt] = MFMA16(afa, pqf[nt][0], accB[mt][nt]);
                    accB[mt][nt] = MFMA16(afb, pqf[nt][1], accB[mt][nt]);
                }
            }
            #pragma unroll
            for (int mt = 0; mt < 2; mt++)
                #pragma unroll
                for (int nt = 0; nt < 3; nt++)
                    #pragma unroll
                    for (int r = 0; r < 4; r++)
                        Bfs[wave][mt * 16 + quad * 4 + r][nt * 16 + m16] = accB[mt][nt][r];
        }

        // ---- gather + combine + in-register online softmax ----
        float sv[2][4];
        float tmax[4] = {NEG_BIG, NEG_BIG, NEG_BIG, NEG_BIG};
        #pragma unroll
        for (int n = 0; n < 2; n++) {
            #pragma unroll
            for (int r = 0; r < 4; r++) {
                int qq = quad * 4 + r;
                int kc = n * 16 + m16;
                float av = Afs[wave][qq][qq - kc + 31];
                float bv = Bfs[wave][kc][kc - qq + 15];
                float x = (accS[n][r] + av + bv) * inv_scale;
                x = mkk[s][kc] ? x : NEG_BIG;
                sv[n][r] = x;
                tmax[r] = fmaxf(tmax[r], x);
            }
        }
        float alpha[4], psum[4];
        #pragma unroll
        for (int r = 0; r < 4; r++) {
            float tm = tmax[r];
            tm = fmaxf(tm, __shfl_xor(tm, 1));
            tm = fmaxf(tm, __shfl_xor(tm, 2));
            tm = fmaxf(tm, __shfl_xor(tm, 4));
            tm = fmaxf(tm, __shfl_xor(tm, 8));
            float mo = mreg[r];
            float mn = fmaxf(mo, tm);
            alpha[r] = __expf(mo - mn);
            mreg[r] = mn;
        }
        #pragma unroll
        for (int r = 0; r < 4; r++) psum[r] = 0.f;
        #pragma unroll
        for (int n = 0; n < 2; n++) {
            #pragma unroll
            for (int r = 0; r < 4; r++) {
                float p = (sv[n][r] > -1.5e38f) ? __expf(sv[n][r] - mreg[r]) : 0.0f;
                unsigned short pb = f2b(p);
                Pls[wave][quad * 4 + r][n * 16 + m16] = pb;
                psum[r] += b2f(pb);
            }
        }
        #pragma unroll
        for (int r = 0; r < 4; r++) {
            float ps = psum[r];
            ps += __shfl_xor(ps, 1);
            ps += __shfl_xor(ps, 2);
            ps += __shfl_xor(ps, 4);
            ps += __shfl_xor(ps, 8);
            lreg[r] = lreg[r] * alpha[r] + ps;
        }
        // ---- rescale O, then PV ----
        #pragma unroll
        for (int nt = 0; nt < 4; nt++)
            #pragma unroll
            for (int r = 0; r < 4; r++) accO[nt][r] *= alpha[r];
        {
            bf16x8 pf = *(const bf16x8*)&Pls[wave][m16][quad * 8];
            #pragma unroll
            for (int nt = 0; nt < 4; nt++) {
                int d = nt * 16 + m16;
                int kq = (quad ^ ((d >> 3) & 3)) * 8;
                bf16x8 vf = *(const bf16x8*)&Vt[s][d][kq];
                accO[nt] = MFMA16(pf, vf, accO[nt]);
            }
        }
        __syncthreads();   // tile fully consumed before next restage
    }

    // ---- merge the two k-halves per q-strip (flash split-k merge) ----
    __syncthreads();       // all Bfs gathers done -> safe to alias merge buffer
    float* mo = &Bfs[0][0][0];  // mergeO[u][row][col]: u*1056 + row*66 + col (2112 floats < 6400)
    if (s == 1) {
        #pragma unroll
        for (int nt = 0; nt < 4; nt++)
            #pragma unroll
            for (int r = 0; r < 4; r++)
                mo[u * 1056 + (quad * 4 + r) * 66 + nt * 16 + m16] = accO[nt][r];
        if (m16 == 0) {
            #pragma unroll
            for (int r = 0; r < 4; r++) {
                mergeML[u][0][quad * 4 + r] = mreg[r];
                mergeML[u][1][quad * 4 + r] = lreg[r];
            }
        }
    }
    __syncthreads();
    if (s == 0) {
        #pragma unroll
        for (int r = 0; r < 4; r++) {
            int row = quad * 4 + r;
            float m1 = mergeML[u][0][row], l1 = mergeML[u][1][row];
            float m0 = mreg[r], l0 = lreg[r];
            float mt = fmaxf(m0, m1);
            float a0 = __expf(m0 - mt), a1 = __expf(m1 - mt);
            float lt = l0 * a0 + l1 * a1;
            float inv = lt > 0.0f ? 1.0f / lt : 0.0f;
            inv *= (float)am[b * SEQ + q0 + u * 16 + row];
            #pragma unroll
            for (int nt = 0; nt < 4; nt++) {
                float o1 = mo[u * 1056 + row * 66 + nt * 16 + m16];
                float val = (accO[nt][r] * a0 + o1 * a1) * inv;
                ctx[(size_t)(b * SEQ + q0 + u * 16 + row) * HID + hh * HEAD + nt * 16 + m16] = f2b(val);
            }
        }
    }
}

// ---------------- output copy / classifier (fp32 out) ----------------
__global__ void copy_f_kernel(const float* __restrict__ in, float* __restrict__ out, int n) {
    int i = blockIdx.x * 256 + threadIdx.x;
    if (i < n) out[i] = in[i];
}
__global__ void cls_kernel(const float* __restrict__ h, const float* __restrict__ cls_w,
                           const float* __restrict__ cls_b, float* __restrict__ out) {
    int t = blockIdx.x, v = threadIdx.x;
    if (v < VOCAB) {
        const float* hr = h + (size_t)t * HID;
        const float* wr = cls_w + (size_t)v * HID;
        float acc = cls_b[v];
        for (int d = 0; d < HID; d++) acc += hr[d] * wr[d];
        out[t * VOCAB + v] = acc;
    }
}

extern "C" void kernel_launch(void* const* d_in, const int* in_sizes, int n_in,
                              void* d_out, int out_size, void* d_ws, size_t ws_size,
                              hipStream_t stream) {
    const int* x     = (const int*)d_in[0];
    const int* am    = (const int*)d_in[1];
    const float* word_emb = (const float*)d_in[2];
    const float* emb_g    = (const float*)d_in[3];
    const float* emb_b    = (const float*)d_in[4];
    const float* rel_emb  = (const float*)d_in[5];
    const float* Wq  = (const float*)d_in[6];  const float* bq  = (const float*)d_in[7];
    const float* Wk  = (const float*)d_in[8];  const float* bk  = (const float*)d_in[9];
    const float* Wv  = (const float*)d_in[10]; const float* bv  = (const float*)d_in[11];
    const float* Wpk = (const float*)d_in[12]; const float* bpk = (const float*)d_in[13];
    const float* Wpq = (const float*)d_in[14]; const float* bpq = (const float*)d_in[15];
    const float* Wo  = (const float*)d_in[16]; const float* bo  = (const float*)d_in[17];
    const float* ln1g = (const float*)d_in[18]; const float* ln1b = (const float*)d_in[19];
    const float* W1  = (const float*)d_in[20]; const float* b1  = (const float*)d_in[21];
    const float* W2  = (const float*)d_in[22]; const float* b2  = (const float*)d_in[23];
    const float* ln2g = (const float*)d_in[24]; const float* ln2b = (const float*)d_in[25];
    const float* cls_w = (const float*)d_in[26]; const float* cls_b = (const float*)d_in[27];

    char* wsb = (char*)d_ws;
    const size_t NEED_BIG = 107u << 20;   // 23 MB activations + 84 MB bf16 weights

    if (ws_size >= NEED_BIG) {
        // ---- big-workspace path: preconverted transposed bf16 weights ----
        float* h  = (float*)wsb;                                      // 4 MB
        float* t1 = (float*)(wsb + (4u << 20));                       // 4 MB (split-K part 0)
        float* t2 = (float*)(wsb + (8u << 20));                       // 4 MB (split-K part 1)
        unsigned short* qb   = (unsigned short*)(wsb + (12u << 20));  // 2 MB
        unsigned short* kb   = (unsigned short*)(wsb + (14u << 20));  // 2 MB
        unsigned short* vb   = (unsigned short*)(wsb + (16u << 20));  // 2 MB
        unsigned short* pkb  = (unsigned short*)(wsb + (18u << 20));  // 1 MB
        unsigned short* pqb  = (unsigned short*)(wsb + (19u << 20));  // 1 MB
        unsigned short* relb = (unsigned short*)(wsb + (20u << 20));  // 1 MB
        unsigned short* hb   = (unsigned short*)(wsb + (21u << 20));  // 2 MB
        unsigned short* ctx  = hb;   // alias: hb dead between attn and add_ln1
        unsigned short* ffb  = qb;   // alias: qb..pqb (8 MB) dead by FF1
        unsigned short* Wqt  = (unsigned short*)(wsb + (23u << 20));  // 6x6 MB: q,k,v,pk,pq,o
        unsigned short* W1t  = (unsigned short*)(wsb + (59u << 20));  // 24 MB
        unsigned short* W2t  = (unsigned short*)(wsb + (83u << 20));  // 24 MB

        const size_t M512 = (size_t)HID * HID;   // elements per 512x512 matrix

        tcvt6_kernel<<<dim3(16, 16, 72), dim3(32, 8), 0, stream>>>(Wq, Wk, Wv, Wpk, Wpq, Wo, Wqt);
        tcvt_kernel<<<dim3(64, 16, 12), dim3(32, 8), 0, stream>>>(W1, W1t, HID, FFDIM);
        tcvt_kernel<<<dim3(16, 64, 12), dim3(32, 8), 0, stream>>>(W2, W2t, FFDIM, HID);
        cvt_rel_kernel<<<dim3(SPAN2 * HID / 1024), dim3(256), 0, stream>>>(rel_emb, relb);
        embed_ln_kernel<<<dim3(TOK), dim3(256), 0, stream>>>(x, am, word_emb, emb_g, emb_b, h, hb);

        for (int l = 0; l < NLAYER; l++) {
            qkvp_gemm<<<dim3(1024), dim3(256), 0, stream>>>(
                hb, relb,
                Wqt + (size_t)(0 * NLAYER + l) * M512, Wqt + (size_t)(1 * NLAYER + l) * M512,
                Wqt + (size_t)(2 * NLAYER + l) * M512, Wqt + (size_t)(3 * NLAYER + l) * M512,
                Wqt + (size_t)(4 * NLAYER + l) * M512,
                bq + l * HID, bk + l * HID, bv + l * HID, bpk + l * HID, bpq + l * HID,
                qb, kb, vb, pkb, pqb);

            attn_kernel<<<dim3(SEQ / 32, BATCH * NHEAD), dim3(256), 0, stream>>>(
                qb, kb, vb, pkb, pqb, am, ctx);

            gemm_bt<false, false, 2><<<dim3(HID / 64, TOK / 64, 2), dim3(256), 0, stream>>>(
                ctx, Wqt + (size_t)(5 * NLAYER + l) * M512, bo + l * HID, t1, HID, HID);
            add_ln2_kernel<<<dim3(TOK), dim3(256), 0, stream>>>(t1, t2, ln1g + l * HID, ln1b + l * HID, h, hb);

            gemm_bt<true, true, 1><<<dim3(FFDIM / 64, TOK / 64, 1), dim3(256), 0, stream>>>(
                hb, W1t + (size_t)l * HID * FFDIM, b1 + l * FFDIM, ffb, FFDIM, HID);
            gemm_bt<false, false, 2><<<dim3(HID / 64, TOK / 64, 2), dim3(256), 0, stream>>>(
                ffb, W2t + (size_t)l * HID * FFDIM, b2 + l * HID, t1, HID, FFDIM);
            add_ln2_kernel<<<dim3(TOK), dim3(256), 0, stream>>>(t1, t2, ln2g + l * HID, ln2b + l * HID, h, hb);
        }

        float* out_f = (float*)d_out;
        copy_f_kernel<<<dim3(TOK * HID / 256), dim3(256), 0, stream>>>(h, out_f, TOK * HID);
        cls_kernel<<<dim3(TOK), dim3(32), 0, stream>>>(h, cls_w, cls_b, out_f + TOK * HID);
        return;
    }

    // ---- fallback path: baseline 19 MB layout, inline fp32->bf16 weight conversion ----
    const size_t NEEDED = 19u << 20;
    if (ws_size < NEEDED) return;
    float* h  = (float*)wsb;                                     // 4 MB
    float* t1 = (float*)(wsb + (4u << 20));                      // 4 MB
    unsigned short* qb   = (unsigned short*)(wsb + (8u << 20));  // 2 MB
    unsigned short* kb   = qb  + (1u << 20);                     // 2 MB
    unsigned short* vb   = kb  + (1u << 20);                     // 2 MB
    unsigned short* pkb  = vb  + (1u << 20);                     // 1 MB
    unsigned short* pqb  = pkb + (1u << 19);                     // 1 MB
    unsigned short* relb = (unsigned short*)(wsb + (16u << 20)); // 1 MB
    unsigned short* hb   = (unsigned short*)(wsb + (17u << 20)); // 2 MB
    unsigned short* ctx  = hb;   // alias: hb dead between V-GEMM and add_ln1
    unsigned short* ffb  = qb;   // alias: q..pq dead by FF1

    cvt_rel_kernel<<<dim3(SPAN2 * HID / 1024), dim3(256), 0, stream>>>(rel_emb, relb);
    embed_ln_kernel<<<dim3(TOK), dim3(256), 0, stream>>>(x, am, word_emb, emb_g, emb_b, h, hb);

    for (int l = 0; l < NLAYER; l++) {
        const float* Wq_l = Wq + (size_t)l * HID * HID;
        const float* Wk_l = Wk + (size_t)l * HID * HID;
        const float* Wv_l = Wv + (size_t)l * HID * HID;
        const float* Wo_l = Wo + (size_t)l * HID * HID;
        const float* Wpk_l = Wpk + (size_t)l * HID * HID;
        const float* Wpq_l = Wpq + (size_t)l * HID * HID;
        const float* W1_l = W1 + (size_t)l * HID * FFDIM;
        const float* W2_l = W2 + (size_t)l * FFDIM * HID;

        mfma_gemm<true,  false><<<dim3(HID/64, TOK/64),   dim3(256), 0, stream>>>(hb,   Wq_l,  bq + l*HID,  qb,  HID, HID);
        mfma_gemm<true,  false><<<dim3(HID/64, TOK/64),   dim3(256), 0, stream>>>(hb,   Wk_l,  bk + l*HID,  kb,  HID, HID);
        mfma_gemm<true,  false><<<dim3(HID/64, TOK/64),   dim3(256), 0, stream>>>(hb,   Wv_l,  bv + l*HID,  vb,  HID, HID);
        mfma_gemm<true,  false><<<dim3(HID/64, SPAN2/64), dim3(256), 0, stream>>>(relb, Wpk_l, bpk + l*HID, pkb, HID, HID);
        mfma_gemm<true,  false><<<dim3(HID/64, SPAN2/64), dim3(256), 0, stream>>>(relb, Wpq_l, bpq + l*HID, pqb, HID, HID);

        attn_kernel<<<dim3(SEQ/32, BATCH*NHEAD), dim3(256), 0, stream>>>(qb, kb, vb, pkb, pqb, am, ctx);

        mfma_gemm<false, false><<<dim3(HID/64, TOK/64),   dim3(256), 0, stream>>>(ctx,  Wo_l,  bo + l*HID,  t1,  HID, HID);
        add_ln_kernel<<<dim3(TOK), dim3(256), 0, stream>>>(t1, ln1g + l*HID, ln1b + l*HID, h, hb);

        mfma_gemm<true,  true ><<<dim3(FFDIM/64, TOK/64), dim3(256), 0, stream>>>(hb,   W1_l,  b1 + l*FFDIM, ffb, FFDIM, HID);
        mfma_gemm<false, false><<<dim3(HID/64, TOK/64),   dim3(256), 0, stream>>>(ffb,  W2_l,  b2 + l*HID,  t1,  HID, FFDIM);
        add_ln_kernel<<<dim3(TOK), dim3(256), 0, stream>>>(t1, ln2g + l*HID, ln2b + l*HID, h, hb);
    }

    float* out_f = (float*)d_out;
    copy_f_kernel<<<dim3(TOK*HID/256), dim3(256), 0, stream>>>(h, out_f, TOK*HID);
    cls_kernel<<<dim3(TOK), dim3(32), 0, stream>>>(h, cls_w, cls_b, out_f + TOK*HID);
}